// Round 1
// baseline (665.616 us; speedup 1.0000x reference)
//
#include <hip/hip_runtime.h>
#include <math.h>

#define NN 50000
#define EE 800000
#define ETOT 850000   // EE + NN self loops
#define INF 128
#define DD 64

// ---------- helpers ----------
__device__ __forceinline__ float wsum(float v) {
#pragma unroll
    for (int m = 1; m < 64; m <<= 1) v += __shfl_xor(v, m, 64);
    return v;
}

__device__ __forceinline__ unsigned fkey(float f) {
    unsigned u = __float_as_uint(f);
    return (u >> 31) ? ~u : (u | 0x80000000u);
}
__device__ __forceinline__ float fdecode(unsigned k) {
    return (k >> 31) ? __uint_as_float(k ^ 0x80000000u) : __uint_as_float(~k);
}

// ---------- K0: init m2key ----------
__global__ void k_init(unsigned* __restrict__ m2key) {
    int t = blockIdx.x * blockDim.x + threadIdx.x;
    if (t < NN) m2key[t] = fkey(-INFINITY);
}

// ---------- K1: per-node transform (GEMM + hyperbolic maps + att scalars) ----------
__global__ __launch_bounds__(256) void k_node(
    const float* __restrict__ x, const float* __restrict__ W,
    const float* __restrict__ b, const float* __restrict__ att,
    float* __restrict__ ox, float* __restrict__ lx,
    float* __restrict__ ai, float* __restrict__ aj)
{
    __shared__ float Wl[INF * (DD - 1)];   // 128*63 = 8064 f32
    __shared__ float bl[DD - 1];
    for (int t = threadIdx.x; t < INF * (DD - 1); t += blockDim.x) Wl[t] = W[t];
    for (int t = threadIdx.x; t < DD - 1; t += blockDim.x) bl[t] = b[t];
    __syncthreads();

    const int wid  = threadIdx.x >> 6;
    const int lane = threadIdx.x & 63;
    const int n = blockIdx.x * 4 + wid;
    if (n >= NN) return;

    const int col = (lane == 0) ? 0 : lane - 1;   // lane l>=1 owns xs[l-1]
    const float* xr = x + (size_t)n * INF;
    float acc = 0.f;
#pragma unroll 8
    for (int k = 0; k < INF; ++k) {
        acc = fmaf(xr[k], Wl[k * (DD - 1) + col], acc);
    }
    float xs = (lane == 0) ? 0.f : (acc + bl[col]);

    float ss = wsum(xs * xs);
    float t   = sqrtf(ss + 1.0f);             // C = 1
    float nrm = sqrtf(ss + 1e-15f);
    float d0  = acoshf(fmaxf(t, 1.0f + 1e-6f));
    float scl = d0 / nrm;

    float oxv = (lane == 0) ? t : xs;
    float lxv = (lane == 0) ? 0.f : scl * xs;
    ox[(size_t)n * DD + lane] = oxv;
    lx[(size_t)n * DD + lane] = lxv;

    float aiv = wsum(lxv * att[lane]);
    float ajv = wsum(lxv * att[DD + lane]);
    if (lane == 0) { ai[n] = aiv; aj[n] = ajv; }
}

// ---------- edge index helper ----------
__device__ __forceinline__ void edge_ij(const int* __restrict__ ei0,
                                        const int* __restrict__ ei1,
                                        int e, int& i, int& j) {
    if (e < EE) { i = ei0[e]; j = ei1[e]; }
    else        { i = e - EE; j = i; }
}

// ---------- P1: sqd per edge + segment max (wave per edge) ----------
__global__ __launch_bounds__(256) void k_sqd(
    const int* __restrict__ ei0, const int* __restrict__ ei1,
    const float* __restrict__ ox, float* __restrict__ ebuf,
    float* __restrict__ m1)
{
    const int gw   = (blockIdx.x * blockDim.x + threadIdx.x) >> 6;
    const int lane = threadIdx.x & 63;
    if (gw >= ETOT) return;
    int i, j; edge_ij(ei0, ei1, gw, i, j);

    float oi = ox[(size_t)i * DD + lane];
    float oj = ox[(size_t)j * DD + lane];
    float p = oi * oj;
    if (lane == 0) p = -p;
    float inner = wsum(p);
    if (lane == 0) {
        float arg = fmaxf(-inner, 1.0f + 1e-6f);
        float s = acoshf(arg);
        float sq = s * s;
        ebuf[gw] = sq;
        atomicMax((int*)&m1[i], __float_as_int(sq));  // sq >= 0 -> int order ok
    }
}

// ---------- P2: e1 = exp(sqd - m1), sum ----------
__global__ __launch_bounds__(256) void k_exp1(
    const int* __restrict__ ei0, const int* __restrict__ ei1,
    float* __restrict__ ebuf, const float* __restrict__ m1,
    float* __restrict__ s1)
{
    int e = blockIdx.x * blockDim.x + threadIdx.x;
    if (e >= ETOT) return;
    int i, j; edge_ij(ei0, ei1, e, i, j);
    float v = expf(ebuf[e] - m1[i]);
    ebuf[e] = v;
    atomicAdd(&s1[i], v);
}

// ---------- P3: alpha = (a_i+a_j)*w1, leaky, segment max ----------
__global__ __launch_bounds__(256) void k_alpha(
    const int* __restrict__ ei0, const int* __restrict__ ei1,
    float* __restrict__ ebuf, const float* __restrict__ s1,
    const float* __restrict__ ai, const float* __restrict__ aj,
    unsigned* __restrict__ m2key)
{
    int e = blockIdx.x * blockDim.x + threadIdx.x;
    if (e >= ETOT) return;
    int i, j; edge_ij(ei0, ei1, e, i, j);
    float w1 = ebuf[e] / (s1[i] + 1e-16f);
    float al = (ai[i] + aj[j]) * w1;
    al = (al >= 0.f) ? al : 0.2f * al;
    ebuf[e] = al;
    atomicMax(&m2key[i], fkey(al));
}

// ---------- P4: e2 = exp(alpha - m2), sum ----------
__global__ __launch_bounds__(256) void k_exp2(
    const int* __restrict__ ei0, const int* __restrict__ ei1,
    float* __restrict__ ebuf, const unsigned* __restrict__ m2key,
    float* __restrict__ s2)
{
    int e = blockIdx.x * blockDim.x + threadIdx.x;
    if (e >= ETOT) return;
    int i, j; edge_ij(ei0, ei1, e, i, j);
    float m2 = fdecode(m2key[i]);
    float v = expf(ebuf[e] - m2);
    ebuf[e] = v;
    atomicAdd(&s2[i], v);
}

// ---------- P5: out[i] += w2 * logx[j]  (wave per edge) ----------
__global__ __launch_bounds__(256) void k_scatter(
    const int* __restrict__ ei0, const int* __restrict__ ei1,
    const float* __restrict__ ebuf, const float* __restrict__ s2,
    const float* __restrict__ lx, float* __restrict__ out)
{
    const int gw   = (blockIdx.x * blockDim.x + threadIdx.x) >> 6;
    const int lane = threadIdx.x & 63;
    if (gw >= ETOT) return;
    int i, j; edge_ij(ei0, ei1, gw, i, j);
    float w2 = ebuf[gw] / (s2[i] + 1e-16f);
    float v = w2 * lx[(size_t)j * DD + lane];
    atomicAdd(&out[(size_t)i * DD + lane], v);
}

// ---------- K7: epilogue exp-map (wave per node), in-place on out ----------
__global__ __launch_bounds__(256) void k_epi(float* __restrict__ out)
{
    const int wid  = threadIdx.x >> 6;
    const int lane = threadIdx.x & 63;
    const int n = blockIdx.x * 4 + wid;
    if (n >= NN) return;
    float u = out[(size_t)n * DD + lane];
    float usp = (lane == 0) ? 0.f : fmaxf(u, 0.f);
    float ss = wsum(usp * usp);
    float un = sqrtf(ss + 1e-15f);
    float sc = sinhf(un) / un;
    float sp = sc * usp;
    float time = sqrtf(sc * sc * ss + 1.0f);
    out[(size_t)n * DD + lane] = (lane == 0) ? time : sp;
}

extern "C" void kernel_launch(void* const* d_in, const int* in_sizes, int n_in,
                              void* d_out, int out_size, void* d_ws, size_t ws_size,
                              hipStream_t stream) {
    const float* x   = (const float*)d_in[0];
    const float* W   = (const float*)d_in[1];
    const float* b   = (const float*)d_in[2];
    const float* att = (const float*)d_in[3];
    const int*   ei  = (const int*)d_in[4];
    const int* ei0 = ei;
    const int* ei1 = ei + EE;
    float* out = (float*)d_out;

    // workspace layout (floats)
    float* ws = (float*)d_ws;
    float*    ox    = ws;                         // N*64
    float*    lx    = ox + (size_t)NN * DD;       // N*64
    float*    ai    = lx + (size_t)NN * DD;       // N
    float*    aj    = ai + NN;                    // N
    float*    m1    = aj + NN;                    // N
    float*    s1    = m1 + NN;                    // N
    unsigned* m2key = (unsigned*)(s1 + NN);       // N
    float*    s2    = (float*)(m2key + NN);       // N
    float*    ebuf  = s2 + NN;                    // ETOT

    // init: zeros for m1/s1/s2 and output accumulator; -inf key for m2
    hipMemsetAsync(m1, 0, sizeof(float) * NN, stream);
    hipMemsetAsync(s1, 0, sizeof(float) * NN, stream);
    hipMemsetAsync(s2, 0, sizeof(float) * NN, stream);
    hipMemsetAsync(out, 0, sizeof(float) * (size_t)NN * DD, stream);
    k_init<<<(NN + 255) / 256, 256, 0, stream>>>(m2key);

    // node transform
    k_node<<<(NN + 3) / 4, 256, 0, stream>>>(x, W, b, att, ox, lx, ai, aj);

    // edge passes
    const int gw_blocks = (ETOT + 3) / 4;     // wave-per-edge kernels
    const int th_blocks = (ETOT + 255) / 256; // thread-per-edge kernels
    k_sqd    <<<gw_blocks, 256, 0, stream>>>(ei0, ei1, ox, ebuf, m1);
    k_exp1   <<<th_blocks, 256, 0, stream>>>(ei0, ei1, ebuf, m1, s1);
    k_alpha  <<<th_blocks, 256, 0, stream>>>(ei0, ei1, ebuf, s1, ai, aj, m2key);
    k_exp2   <<<th_blocks, 256, 0, stream>>>(ei0, ei1, ebuf, m2key, s2);
    k_scatter<<<gw_blocks, 256, 0, stream>>>(ei0, ei1, ebuf, s2, lx, out);

    // epilogue
    k_epi<<<(NN + 3) / 4, 256, 0, stream>>>(out);
}

// Round 2
// 312.913 us; speedup vs baseline: 2.1272x; 2.1272x over previous
//
#include <hip/hip_runtime.h>
#include <math.h>
#include <float.h>

#define NN 50000
#define EE 800000
#define ETOT 850000   // EE + NN self loops
#define INF 128
#define DD 64

// ---------- helpers ----------
__device__ __forceinline__ float wsum64(float v) {
#pragma unroll
    for (int m = 1; m < 64; m <<= 1) v += __shfl_xor(v, m, 64);
    return v;
}

// ---------- K1: per-node transform (GEMM + hyperbolic maps + att scalars) ----------
__global__ __launch_bounds__(256) void k_node(
    const float* __restrict__ x, const float* __restrict__ W,
    const float* __restrict__ b, const float* __restrict__ att,
    float* __restrict__ ox, float* __restrict__ lx,
    float* __restrict__ ai, float* __restrict__ aj)
{
    __shared__ float Wl[INF * (DD - 1)];   // 128*63 = 8064 f32
    __shared__ float bl[DD - 1];
    for (int t = threadIdx.x; t < INF * (DD - 1); t += blockDim.x) Wl[t] = W[t];
    for (int t = threadIdx.x; t < DD - 1; t += blockDim.x) bl[t] = b[t];
    __syncthreads();

    const int wid  = threadIdx.x >> 6;
    const int lane = threadIdx.x & 63;
    const int n = blockIdx.x * 4 + wid;
    if (n >= NN) return;

    const int col = (lane == 0) ? 0 : lane - 1;   // lane l>=1 owns xs[l-1]
    const float* xr = x + (size_t)n * INF;
    float acc = 0.f;
#pragma unroll 8
    for (int k = 0; k < INF; ++k) {
        acc = fmaf(xr[k], Wl[k * (DD - 1) + col], acc);
    }
    float xs = (lane == 0) ? 0.f : (acc + bl[col]);

    float ss = wsum64(xs * xs);
    float t   = sqrtf(ss + 1.0f);             // C = 1
    float nrm = sqrtf(ss + 1e-15f);
    float d0  = acoshf(fmaxf(t, 1.0f + 1e-6f));
    float scl = d0 / nrm;

    float oxv = (lane == 0) ? t : xs;
    float lxv = (lane == 0) ? 0.f : scl * xs;
    ox[(size_t)n * DD + lane] = oxv;
    lx[(size_t)n * DD + lane] = lxv;

    float aiv = wsum64(lxv * att[lane]);
    float ajv = wsum64(lxv * att[DD + lane]);
    if (lane == 0) { ai[n] = aiv; aj[n] = ajv; }
}

// ---------- CSR build ----------
__global__ __launch_bounds__(256) void k_deg(
    const int* __restrict__ ei0, int* __restrict__ deg, int* __restrict__ posbuf)
{
    int e = blockIdx.x * blockDim.x + threadIdx.x;
    if (e >= ETOT) return;
    int i = (e < EE) ? ei0[e] : (e - EE);
    posbuf[e] = atomicAdd(&deg[i], 1);
}

// inclusive scan of deg -> rowptr[1..NN] (partial, per block), block sums -> bsum
__global__ __launch_bounds__(256) void k_scan1(
    const int* __restrict__ deg, int* __restrict__ rowptr, int* __restrict__ bsum)
{
    __shared__ int tmp[256];
    int tid = threadIdx.x;
    int gid = blockIdx.x * 256 + tid;
    int v = (gid < NN) ? deg[gid] : 0;
    tmp[tid] = v; __syncthreads();
    for (int off = 1; off < 256; off <<= 1) {
        int t = (tid >= off) ? tmp[tid - off] : 0;
        __syncthreads();
        tmp[tid] += t;
        __syncthreads();
    }
    if (gid < NN) rowptr[gid + 1] = tmp[tid];
    if (tid == 255) bsum[blockIdx.x] = tmp[255];
}

__global__ __launch_bounds__(256) void k_scan2(int* __restrict__ bsum, int nb)
{
    __shared__ int tmp[256];
    int tid = threadIdx.x;
    int v = (tid < nb) ? bsum[tid] : 0;
    tmp[tid] = v; __syncthreads();
    for (int off = 1; off < 256; off <<= 1) {
        int t = (tid >= off) ? tmp[tid - off] : 0;
        __syncthreads();
        tmp[tid] += t;
        __syncthreads();
    }
    if (tid < nb) bsum[tid] = tmp[tid];
}

__global__ __launch_bounds__(256) void k_scan3(
    int* __restrict__ rowptr, const int* __restrict__ bsum)
{
    int gid = blockIdx.x * 256 + threadIdx.x;
    if (gid < NN) {
        int add = (blockIdx.x > 0) ? bsum[blockIdx.x - 1] : 0;
        rowptr[gid + 1] += add;
    }
    if (gid == 0) rowptr[0] = 0;
}

__global__ __launch_bounds__(256) void k_place(
    const int* __restrict__ ei0, const int* __restrict__ ei1,
    const int* __restrict__ rowptr, const int* __restrict__ posbuf,
    int* __restrict__ colA)
{
    int e = blockIdx.x * blockDim.x + threadIdx.x;
    if (e >= ETOT) return;
    int i, j;
    if (e < EE) { i = ei0[e]; j = ei1[e]; }
    else        { i = e - EE; j = i; }
    colA[rowptr[i] + posbuf[e]] = j;
}

// ---------- fused edge phase + epilogue: one wave per node ----------
__global__ __launch_bounds__(256) void k_fused(
    const int* __restrict__ rowptr, const int* __restrict__ colA,
    const float* __restrict__ ox, const float* __restrict__ lx,
    const float* __restrict__ ai, const float* __restrict__ aj,
    float* __restrict__ ebuf, float* __restrict__ y)
{
    const int wid  = threadIdx.x >> 6;
    const int lane = threadIdx.x & 63;
    const int n = blockIdx.x * 4 + wid;
    if (n >= NN) return;

    const int base = rowptr[n];
    const int deg  = rowptr[n + 1] - base;
    const int sub  = lane & 15;   // lane within 16-lane group
    const int grp  = lane >> 4;   // which of 4 edges per sweep-A step

    const float4 oxi = ((const float4*)ox)[(size_t)n * 16 + sub];
    const float sgn = (sub == 0) ? -1.f : 1.f;   // Minkowski sign on time comp
    const float aii = ai[n];

    // ---- sweep A: sqd per edge, online max+sum (softmax 1) ----
    float m1 = -3.0e38f, s1a = 0.f;
    for (int k0 = 0; k0 < deg; k0 += 4) {
        int ke = k0 + grp;
        bool act = ke < deg;
        int j = act ? colA[base + ke] : 0;
        float4 oj = ((const float4*)ox)[(size_t)j * 16 + sub];
        float p = sgn * oxi.x * oj.x + oxi.y * oj.y + oxi.z * oj.z + oxi.w * oj.w;
#pragma unroll
        for (int m = 1; m < 16; m <<= 1) p += __shfl_xor(p, m, 64);
        if (sub == 0 && act) {
            float arg = fmaxf(-p, 1.0f + 1e-6f);
            float s = acoshf(arg);
            float sq = s * s;
            ebuf[base + ke] = sq;
            float nm = fmaxf(m1, sq);
            s1a = s1a * expf(m1 - nm) + expf(sq - nm);
            m1 = nm;
        }
    }
    // combine 4 group leaders (lanes 0,16,32,48)
#pragma unroll
    for (int off = 16; off < 64; off <<= 1) {
        float om = __shfl_xor(m1, off, 64);
        float os = __shfl_xor(s1a, off, 64);
        float nm = fmaxf(m1, om);
        s1a = s1a * expf(m1 - nm) + os * expf(om - nm);
        m1 = nm;
    }
    const float m1b = __shfl(m1, 0, 64);
    const float s1  = __shfl(s1a, 0, 64) + 1e-16f;

    // ---- sweep B: alpha per edge, online max+sum (softmax 2) ----
    float m2 = -3.0e38f, s2a = 0.f;
    float alv = 0.f;          // fast-path register store (deg <= 64)
    int   jreg = 0;
    for (int k0 = 0; k0 < deg; k0 += 64) {
        int ke = k0 + lane;
        if (ke < deg) {
            float sq = ebuf[base + ke];
            int j = colA[base + ke];
            float w1 = expf(sq - m1b) / s1;
            float al = (aii + aj[j]) * w1;
            al = (al >= 0.f) ? al : 0.2f * al;
            if (deg > 64) ebuf[base + ke] = al;
            else { alv = al; jreg = j; }
            float nm = fmaxf(m2, al);
            s2a = s2a * expf(m2 - nm) + expf(al - nm);
            m2 = nm;
        }
    }
#pragma unroll
    for (int off = 1; off < 64; off <<= 1) {
        float om = __shfl_xor(m2, off, 64);
        float os = __shfl_xor(s2a, off, 64);
        float nm = fmaxf(m2, om);
        s2a = s2a * expf(m2 - nm) + os * expf(om - nm);
        m2 = nm;
    }
    const float m2b = __shfl(m2, 0, 64);
    const float inv = 1.f / (__shfl(s2a, 0, 64) + 1e-16f);

    // ---- sweep C: out[lane] = sum_e w2 * lx[j][lane] ----
    float acc = 0.f;
    if (deg <= 64) {
        float w2 = (lane < deg) ? expf(alv - m2b) * inv : 0.f;
        for (int k = 0; k < deg; ++k) {
            float w = __shfl(w2, k, 64);
            int   j = __shfl(jreg, k, 64);
            acc = fmaf(w, lx[(size_t)j * DD + lane], acc);
        }
    } else {
        for (int k = 0; k < deg; ++k) {
            float al = ebuf[base + k];
            int   j  = colA[base + k];
            float w  = expf(al - m2b) * inv;
            acc = fmaf(w, lx[(size_t)j * DD + lane], acc);
        }
    }

    // ---- fused epilogue: relu + exp map ----
    float usp = (lane == 0) ? 0.f : fmaxf(acc, 0.f);
    float ss = wsum64(usp * usp);
    float un = sqrtf(ss + 1e-15f);
    float sc = sinhf(un) / un;
    float sp = sc * usp;
    float time = sqrtf(sc * sc * ss + 1.0f);
    y[(size_t)n * DD + lane] = (lane == 0) ? time : sp;
}

extern "C" void kernel_launch(void* const* d_in, const int* in_sizes, int n_in,
                              void* d_out, int out_size, void* d_ws, size_t ws_size,
                              hipStream_t stream) {
    const float* x   = (const float*)d_in[0];
    const float* W   = (const float*)d_in[1];
    const float* b   = (const float*)d_in[2];
    const float* att = (const float*)d_in[3];
    const int*   ei  = (const int*)d_in[4];
    const int* ei0 = ei;
    const int* ei1 = ei + EE;
    float* out = (float*)d_out;

    // workspace layout
    float* ws = (float*)d_ws;
    float* ox = ws;                                   // N*64 (16B aligned)
    float* lx = ox + (size_t)NN * DD;                 // N*64 (16B aligned)
    float* ai = lx + (size_t)NN * DD;                 // N
    float* aj = ai + NN;                              // N
    int*   deg    = (int*)(aj + NN);                  // N
    int*   rowptr = deg + NN;                         // N+1
    int*   bsum   = rowptr + NN + 1;                  // 256
    int*   colA   = bsum + 256;                       // ETOT
    int*   posbuf = colA + ETOT;                      // ETOT (overlaid with ebuf)
    float* ebuf   = (float*)posbuf;                   // ETOT (reuse after k_place)

    const int th_blocks = (ETOT + 255) / 256;
    const int nb1 = (NN + 255) / 256;                 // 196 <= 256

    hipMemsetAsync(deg, 0, sizeof(int) * NN, stream);

    // node transform (independent of CSR build)
    k_node<<<(NN + 3) / 4, 256, 0, stream>>>(x, W, b, att, ox, lx, ai, aj);

    // CSR build
    k_deg  <<<th_blocks, 256, 0, stream>>>(ei0, deg, posbuf);
    k_scan1<<<nb1, 256, 0, stream>>>(deg, rowptr, bsum);
    k_scan2<<<1, 256, 0, stream>>>(bsum, nb1);
    k_scan3<<<nb1, 256, 0, stream>>>(rowptr, bsum);
    k_place<<<th_blocks, 256, 0, stream>>>(ei0, ei1, rowptr, posbuf, colA);

    // fused edge phase + epilogue
    k_fused<<<(NN + 3) / 4, 256, 0, stream>>>(rowptr, colA, ox, lx, ai, aj, ebuf, out);
}

// Round 3
// 176.341 us; speedup vs baseline: 3.7746x; 1.7745x over previous
//
#include <hip/hip_runtime.h>
#include <math.h>

#define NN 50000
#define EE 800000
#define ETOT 850000   // EE + NN self loops
#define INF 128
#define DD 64

// ---------- helpers ----------
__device__ __forceinline__ float wsum64(float v) {
#pragma unroll
    for (int m = 1; m < 64; m <<= 1) v += __shfl_xor(v, m, 64);
    return v;
}
__device__ __forceinline__ float wmax64(float v) {
#pragma unroll
    for (int m = 1; m < 64; m <<= 1) v = fmaxf(v, __shfl_xor(v, m, 64));
    return v;
}
__device__ __forceinline__ float rlane(float v, int k) {   // k must be compile-time
    return __int_as_float(__builtin_amdgcn_readlane(__float_as_int(v), k));
}

// ---------- K1: per-node transform; W held in VGPRs (one col per lane) ----------
__global__ __launch_bounds__(256) void k_node(
    const float* __restrict__ x, const float* __restrict__ W,
    const float* __restrict__ b, const float* __restrict__ att,
    float* __restrict__ ox, float* __restrict__ lx,
    float* __restrict__ ai, float* __restrict__ aj)
{
    const int lane = threadIdx.x & 63;
    const int wid  = threadIdx.x >> 6;
    const int wgid = blockIdx.x * 4 + wid;
    const int nw   = gridDim.x * 4;

    const int col = (lane == 0) ? 0 : lane - 1;   // lane l>=1 owns xs col l-1
    float wreg[INF];
#pragma unroll
    for (int k = 0; k < INF; ++k) wreg[k] = W[k * (DD - 1) + col];
    const float bcol = b[col];
    const float atti = att[lane];
    const float attj = att[DD + lane];

    if (wgid >= NN) return;
    // prefetch first node's x row
    float nxv0 = x[(size_t)wgid * INF + lane];
    float nxv1 = x[(size_t)wgid * INF + 64 + lane];

    for (int n = wgid; n < NN; n += nw) {
        float xv0 = nxv0, xv1 = nxv1;
        int np = n + nw;
        if (np < NN) {
            nxv0 = x[(size_t)np * INF + lane];
            nxv1 = x[(size_t)np * INF + 64 + lane];
        }
        float acc0 = 0.f, acc1 = 0.f;
#pragma unroll
        for (int k = 0; k < 64; k += 2) {
            acc0 = fmaf(rlane(xv0, k),     wreg[k],     acc0);
            acc1 = fmaf(rlane(xv0, k + 1), wreg[k + 1], acc1);
        }
#pragma unroll
        for (int k = 0; k < 64; k += 2) {
            acc0 = fmaf(rlane(xv1, k),     wreg[64 + k],     acc0);
            acc1 = fmaf(rlane(xv1, k + 1), wreg[64 + k + 1], acc1);
        }
        float xs = (lane == 0) ? 0.f : (acc0 + acc1 + bcol);

        float ss  = wsum64(xs * xs);
        float t   = sqrtf(ss + 1.0f);             // C = 1
        float nrm = sqrtf(ss + 1e-15f);
        float d0  = acoshf(fmaxf(t, 1.0f + 1e-6f));
        float scl = d0 / nrm;

        float oxv = (lane == 0) ? t : xs;
        float lxv = (lane == 0) ? 0.f : scl * xs;
        ox[(size_t)n * DD + lane] = oxv;
        lx[(size_t)n * DD + lane] = lxv;

        float aiv = wsum64(lxv * atti);
        float ajv = wsum64(lxv * attj);
        if (lane == 0) { ai[n] = aiv; aj[n] = ajv; }
    }
}

// ---------- CSR build ----------
__global__ __launch_bounds__(256) void k_deg(
    const int* __restrict__ ei0, int* __restrict__ deg, int* __restrict__ posbuf)
{
    int e = blockIdx.x * blockDim.x + threadIdx.x;
    if (e >= ETOT) return;
    int i = (e < EE) ? ei0[e] : (e - EE);
    posbuf[e] = atomicAdd(&deg[i], 1);
}

__global__ __launch_bounds__(256) void k_scan1(
    const int* __restrict__ deg, int* __restrict__ rowptr, int* __restrict__ bsum)
{
    __shared__ int tmp[256];
    int tid = threadIdx.x;
    int gid = blockIdx.x * 256 + tid;
    int v = (gid < NN) ? deg[gid] : 0;
    tmp[tid] = v; __syncthreads();
    for (int off = 1; off < 256; off <<= 1) {
        int t = (tid >= off) ? tmp[tid - off] : 0;
        __syncthreads();
        tmp[tid] += t;
        __syncthreads();
    }
    if (gid < NN) rowptr[gid + 1] = tmp[tid];
    if (tid == 255) bsum[blockIdx.x] = tmp[255];
}

__global__ __launch_bounds__(256) void k_scan2(int* __restrict__ bsum, int nb)
{
    __shared__ int tmp[256];
    int tid = threadIdx.x;
    int v = (tid < nb) ? bsum[tid] : 0;
    tmp[tid] = v; __syncthreads();
    for (int off = 1; off < 256; off <<= 1) {
        int t = (tid >= off) ? tmp[tid - off] : 0;
        __syncthreads();
        tmp[tid] += t;
        __syncthreads();
    }
    if (tid < nb) bsum[tid] = tmp[tid];
}

__global__ __launch_bounds__(256) void k_scan3(
    int* __restrict__ rowptr, const int* __restrict__ bsum)
{
    int gid = blockIdx.x * 256 + threadIdx.x;
    if (gid < NN) {
        int add = (blockIdx.x > 0) ? bsum[blockIdx.x - 1] : 0;
        rowptr[gid + 1] += add;
    }
    if (gid == 0) rowptr[0] = 0;
}

__global__ __launch_bounds__(256) void k_place(
    const int* __restrict__ ei0, const int* __restrict__ ei1,
    const int* __restrict__ rowptr, const int* __restrict__ posbuf,
    int* __restrict__ colA)
{
    int e = blockIdx.x * blockDim.x + threadIdx.x;
    if (e >= ETOT) return;
    int i, j;
    if (e < EE) { i = ei0[e]; j = ei1[e]; }
    else        { i = e - EE; j = i; }
    colA[rowptr[i] + posbuf[e]] = j;
}

// ---------- fused edge phase + epilogue: one wave per node ----------
__global__ __launch_bounds__(256) void k_fused(
    const int* __restrict__ rowptr, const int* __restrict__ colA,
    const float* __restrict__ ox, const float* __restrict__ lx,
    const float* __restrict__ ai, const float* __restrict__ aj,
    float* __restrict__ ebuf, float* __restrict__ y)
{
    const int lane = threadIdx.x & 63;
    const int wid  = threadIdx.x >> 6;
    const int n = blockIdx.x * 4 + wid;
    if (n >= NN) return;

    const int base = rowptr[n];
    const int deg  = rowptr[n + 1] - base;
    const float aii = ai[n];

    const int s = lane & 3;      // dim-quarter within 4-lane group (16 dims)
    const int g = lane >> 2;     // group id 0..15 (one edge per group per step)

    // this lane's 16-dim fragment of ox[n]
    const float4* oxn = (const float4*)(ox + (size_t)n * DD + s * 16);
    const float4 xa = oxn[0], xb = oxn[1], xc = oxn[2], xd = oxn[3];
    const float sgn0 = (s == 0) ? -1.f : 1.f;   // Minkowski sign on dim 0

    float acc = 0.f;

    if (deg <= 64) {
        // ---- load all edge targets (lane-per-edge), prefetch aj gather ----
        const int  ecl  = min(lane, deg - 1);
        const int  jreg = colA[base + ecl];
        const float ajv = (lane < deg) ? aj[jreg] : 0.f;

        float sq0 = -3e38f, sq1 = -3e38f, sq2 = -3e38f, sq3 = -3e38f;
        float m1 = -3e38f;

        auto stepA = [&](int t) -> float {
            int e = g + 16 * t;
            bool act = e < deg;
            int ec = min(e, deg - 1);
            int j = __shfl(jreg, ec, 64);
            const float4* oj = (const float4*)(ox + (size_t)j * DD + s * 16);
            float4 a = oj[0], bq = oj[1], c = oj[2], d = oj[3];
            float p = sgn0 * xa.x * a.x;
            p = fmaf(xa.y, a.y, p);  p = fmaf(xa.z, a.z, p);  p = fmaf(xa.w, a.w, p);
            p = fmaf(xb.x, bq.x, p); p = fmaf(xb.y, bq.y, p); p = fmaf(xb.z, bq.z, p); p = fmaf(xb.w, bq.w, p);
            p = fmaf(xc.x, c.x, p);  p = fmaf(xc.y, c.y, p);  p = fmaf(xc.z, c.z, p);  p = fmaf(xc.w, c.w, p);
            p = fmaf(xd.x, d.x, p);  p = fmaf(xd.y, d.y, p);  p = fmaf(xd.z, d.z, p);  p = fmaf(xd.w, d.w, p);
            p += __shfl_xor(p, 1, 64);
            p += __shfl_xor(p, 2, 64);
            float arg = fmaxf(-p, 1.0f + 1e-6f);
            float dd = acoshf(arg);
            float sq = dd * dd;
            sq = act ? sq : -3e38f;
            m1 = fmaxf(m1, sq);
            return sq;
        };
        sq0 = stepA(0);
        if (deg > 16) { sq1 = stepA(1);
            if (deg > 32) { sq2 = stepA(2);
                if (deg > 48) { sq3 = stepA(3); } } }

        // m1 full max (within-group values identical -> 4 steps)
#pragma unroll
        for (int m = 4; m < 64; m <<= 1) m1 = fmaxf(m1, __shfl_xor(m1, m, 64));

        // redistribute sq: lane l owns edge l (computed by group l&15 at step l>>4)
        const int src = 4 * (lane & 15);
        float q0 = __shfl(sq0, src, 64);
        float q1 = __shfl(sq1, src, 64);
        float q2 = __shfl(sq2, src, 64);
        float q3 = __shfl(sq3, src, 64);
        const int t = lane >> 4;
        float qa = (t & 1) ? q1 : q0;
        float qb = (t & 1) ? q3 : q2;
        float sqm = (t & 2) ? qb : qa;

        // ---- dense register softmax chain ----
        const bool act = lane < deg;
        float e1 = act ? expf(sqm - m1) : 0.f;
        float s1 = wsum64(e1) + 1e-16f;
        float al = (aii + ajv) * e1 / s1;
        al = (al >= 0.f) ? al : 0.2f * al;
        float m2 = wmax64(act ? al : -3e38f);
        float p2 = act ? expf(al - m2) : 0.f;
        float s2 = wsum64(p2);
        float w2 = p2 / (s2 + 1e-16f);

        // ---- sweep C: lane-per-dim, 8 gathers in flight ----
        int k = 0;
        for (; k + 8 <= deg; k += 8) {
            float w0 = __shfl(w2, k + 0, 64), wv1 = __shfl(w2, k + 1, 64);
            float wv2 = __shfl(w2, k + 2, 64), wv3 = __shfl(w2, k + 3, 64);
            float wv4 = __shfl(w2, k + 4, 64), wv5 = __shfl(w2, k + 5, 64);
            float wv6 = __shfl(w2, k + 6, 64), wv7 = __shfl(w2, k + 7, 64);
            int j0 = __shfl(jreg, k + 0, 64), j1 = __shfl(jreg, k + 1, 64);
            int j2 = __shfl(jreg, k + 2, 64), j3 = __shfl(jreg, k + 3, 64);
            int j4 = __shfl(jreg, k + 4, 64), j5 = __shfl(jreg, k + 5, 64);
            int j6 = __shfl(jreg, k + 6, 64), j7 = __shfl(jreg, k + 7, 64);
            float v0 = lx[(size_t)j0 * DD + lane], v1 = lx[(size_t)j1 * DD + lane];
            float v2 = lx[(size_t)j2 * DD + lane], v3 = lx[(size_t)j3 * DD + lane];
            float v4 = lx[(size_t)j4 * DD + lane], v5 = lx[(size_t)j5 * DD + lane];
            float v6 = lx[(size_t)j6 * DD + lane], v7 = lx[(size_t)j7 * DD + lane];
            acc = fmaf(w0, v0, acc);  acc = fmaf(wv1, v1, acc);
            acc = fmaf(wv2, v2, acc); acc = fmaf(wv3, v3, acc);
            acc = fmaf(wv4, v4, acc); acc = fmaf(wv5, v5, acc);
            acc = fmaf(wv6, v6, acc); acc = fmaf(wv7, v7, acc);
        }
        for (; k < deg; ++k) {
            float w = __shfl(w2, k, 64);
            int   j = __shfl(jreg, k, 64);
            acc = fmaf(w, lx[(size_t)j * DD + lane], acc);
        }
    } else {
        // ---- generic slow path (deg > 64): ebuf-based, rarely/never taken ----
        float m1 = -3e38f;
        for (int e0 = 0; e0 < deg; e0 += 16) {
            int e = e0 + g;
            bool a_ct = e < deg;
            int ec = min(e, deg - 1);
            int j = colA[base + ec];
            const float4* oj = (const float4*)(ox + (size_t)j * DD + s * 16);
            float4 a = oj[0], bq = oj[1], c = oj[2], d = oj[3];
            float p = sgn0 * xa.x * a.x;
            p = fmaf(xa.y, a.y, p);  p = fmaf(xa.z, a.z, p);  p = fmaf(xa.w, a.w, p);
            p = fmaf(xb.x, bq.x, p); p = fmaf(xb.y, bq.y, p); p = fmaf(xb.z, bq.z, p); p = fmaf(xb.w, bq.w, p);
            p = fmaf(xc.x, c.x, p);  p = fmaf(xc.y, c.y, p);  p = fmaf(xc.z, c.z, p);  p = fmaf(xc.w, c.w, p);
            p = fmaf(xd.x, d.x, p);  p = fmaf(xd.y, d.y, p);  p = fmaf(xd.z, d.z, p);  p = fmaf(xd.w, d.w, p);
            p += __shfl_xor(p, 1, 64);
            p += __shfl_xor(p, 2, 64);
            float arg = fmaxf(-p, 1.0f + 1e-6f);
            float dd = acoshf(arg);
            float sq = dd * dd;
            if (a_ct && s == 0) ebuf[base + e] = sq;
            m1 = fmaxf(m1, a_ct ? sq : -3e38f);
        }
#pragma unroll
        for (int m = 4; m < 64; m <<= 1) m1 = fmaxf(m1, __shfl_xor(m1, m, 64));

        float s1p = 0.f;
        for (int k0 = 0; k0 < deg; k0 += 64) {
            int ke = k0 + lane;
            if (ke < deg) s1p += expf(ebuf[base + ke] - m1);
        }
        float s1 = wsum64(s1p) + 1e-16f;

        float m2l = -3e38f;
        for (int k0 = 0; k0 < deg; k0 += 64) {
            int ke = k0 + lane;
            if (ke < deg) {
                int j = colA[base + ke];
                float e1 = expf(ebuf[base + ke] - m1);
                float al = (aii + aj[j]) * e1 / s1;
                al = (al >= 0.f) ? al : 0.2f * al;
                ebuf[base + ke] = al;
                m2l = fmaxf(m2l, al);
            }
        }
        float m2 = wmax64(m2l);

        float s2p = 0.f;
        for (int k0 = 0; k0 < deg; k0 += 64) {
            int ke = k0 + lane;
            if (ke < deg) s2p += expf(ebuf[base + ke] - m2);
        }
        float s2 = wsum64(s2p) + 1e-16f;

        for (int k = 0; k < deg; ++k) {
            int j = colA[base + k];
            float w = expf(ebuf[base + k] - m2) / s2;
            acc = fmaf(w, lx[(size_t)j * DD + lane], acc);
        }
    }

    // ---- fused epilogue: relu + exp map ----
    float usp = (lane == 0) ? 0.f : fmaxf(acc, 0.f);
    float ss = wsum64(usp * usp);
    float un = sqrtf(ss + 1e-15f);
    float sc = sinhf(un) / un;
    float sp = sc * usp;
    float time = sqrtf(sc * sc * ss + 1.0f);
    y[(size_t)n * DD + lane] = (lane == 0) ? time : sp;
}

extern "C" void kernel_launch(void* const* d_in, const int* in_sizes, int n_in,
                              void* d_out, int out_size, void* d_ws, size_t ws_size,
                              hipStream_t stream) {
    const float* x   = (const float*)d_in[0];
    const float* W   = (const float*)d_in[1];
    const float* b   = (const float*)d_in[2];
    const float* att = (const float*)d_in[3];
    const int*   ei  = (const int*)d_in[4];
    const int* ei0 = ei;
    const int* ei1 = ei + EE;
    float* out = (float*)d_out;

    // workspace layout
    float* ws = (float*)d_ws;
    float* ox = ws;                                   // N*64 (16B aligned)
    float* lx = ox + (size_t)NN * DD;                 // N*64
    float* ai = lx + (size_t)NN * DD;                 // N
    float* aj = ai + NN;                              // N
    int*   deg    = (int*)(aj + NN);                  // N
    int*   rowptr = deg + NN;                         // N+1
    int*   bsum   = rowptr + NN + 1;                  // 256
    int*   colA   = bsum + 256;                       // ETOT
    int*   posbuf = colA + ETOT;                      // ETOT
    float* ebuf   = (float*)posbuf;                   // reuse after k_place (slow path only)

    const int th_blocks = (ETOT + 255) / 256;
    const int nb1 = (NN + 255) / 256;

    hipMemsetAsync(deg, 0, sizeof(int) * NN, stream);

    // node transform (independent of CSR build)
    k_node<<<1024, 256, 0, stream>>>(x, W, b, att, ox, lx, ai, aj);

    // CSR build
    k_deg  <<<th_blocks, 256, 0, stream>>>(ei0, deg, posbuf);
    k_scan1<<<nb1, 256, 0, stream>>>(deg, rowptr, bsum);
    k_scan2<<<1, 256, 0, stream>>>(bsum, nb1);
    k_scan3<<<nb1, 256, 0, stream>>>(rowptr, bsum);
    k_place<<<th_blocks, 256, 0, stream>>>(ei0, ei1, rowptr, posbuf, colA);

    // fused edge phase + epilogue
    k_fused<<<(NN + 3) / 4, 256, 0, stream>>>(rowptr, colA, ox, lx, ai, aj, ebuf, out);
}

// Round 4
// 158.127 us; speedup vs baseline: 4.2094x; 1.1152x over previous
//
#include <hip/hip_runtime.h>
#include <math.h>

#define NN 50000
#define EE 800000
#define ETOT 850000   // EE + NN self loops
#define INF 128
#define DD 64
#define NB_NODE 1024
#define NB_EDGE ((ETOT + 255) / 256)

// ---------- helpers ----------
__device__ __forceinline__ float wsum64(float v) {
#pragma unroll
    for (int m = 1; m < 64; m <<= 1) v += __shfl_xor(v, m, 64);
    return v;
}
__device__ __forceinline__ float wmax64(float v) {
#pragma unroll
    for (int m = 1; m < 64; m <<= 1) v = fmaxf(v, __shfl_xor(v, m, 64));
    return v;
}
__device__ __forceinline__ float rl(float v, int k) {   // k compile-time
    return __int_as_float(__builtin_amdgcn_readlane(__float_as_int(v), k));
}

// Minkowski inner product of wave-uniform row ox[n] (held as xnv, one dim
// per lane) with row ox[j] (full row loaded by THIS lane, 16 float4s).
__device__ __forceinline__ float mink_inner(const float* __restrict__ ox,
                                            int j, float xnv) {
    const float4* ojp = (const float4*)(ox + (size_t)j * DD);
    float4 oj[16];
#pragma unroll
    for (int q = 0; q < 16; ++q) oj[q] = ojp[q];
    float p0 = 0.f, p1 = 0.f, p2 = 0.f, p3 = 0.f;
#pragma unroll
    for (int q = 0; q < 16; ++q) {
        p0 = fmaf(rl(xnv, 4 * q + 0), oj[q].x, p0);
        p1 = fmaf(rl(xnv, 4 * q + 1), oj[q].y, p1);
        p2 = fmaf(rl(xnv, 4 * q + 2), oj[q].z, p2);
        p3 = fmaf(rl(xnv, 4 * q + 3), oj[q].w, p3);
    }
    // time-component term enters with minus sign
    return (p0 + p1 + p2 + p3) - 2.f * rl(xnv, 0) * oj[0].x;
}

// ---------- K1: fused node transform + degree count ----------
__global__ __launch_bounds__(256) void k_node_deg(
    const float* __restrict__ x, const float* __restrict__ W,
    const float* __restrict__ b, const float* __restrict__ att,
    const int* __restrict__ ei0,
    float* __restrict__ ox, float* __restrict__ ai, float2* __restrict__ snd,
    int* __restrict__ deg, int* __restrict__ posbuf)
{
    if (blockIdx.x >= NB_NODE) {
        // ---- degree-count path ----
        int e = (blockIdx.x - NB_NODE) * 256 + threadIdx.x;
        if (e < ETOT) {
            int i = (e < EE) ? ei0[e] : (e - EE);
            posbuf[e] = atomicAdd(&deg[i], 1);
        }
        return;
    }

    // ---- node-transform path: W held in VGPRs (one col per lane) ----
    const int lane = threadIdx.x & 63;
    const int wid  = threadIdx.x >> 6;
    const int wgid = blockIdx.x * 4 + wid;
    const int nw   = NB_NODE * 4;

    const int col = (lane == 0) ? 0 : lane - 1;
    float wreg[INF];
#pragma unroll
    for (int k = 0; k < INF; ++k) wreg[k] = W[k * (DD - 1) + col];
    const float bcol = b[col];
    const float atti = att[lane];
    const float attj = att[DD + lane];

    float nxv0 = x[(size_t)wgid * INF + lane];
    float nxv1 = x[(size_t)wgid * INF + 64 + lane];

    for (int n = wgid; n < NN; n += nw) {
        float xv0 = nxv0, xv1 = nxv1;
        int np = n + nw;
        if (np < NN) {
            nxv0 = x[(size_t)np * INF + lane];
            nxv1 = x[(size_t)np * INF + 64 + lane];
        }
        float acc0 = 0.f, acc1 = 0.f;
#pragma unroll
        for (int k = 0; k < 64; k += 2) {
            acc0 = fmaf(rl(xv0, k),     wreg[k],     acc0);
            acc1 = fmaf(rl(xv0, k + 1), wreg[k + 1], acc1);
        }
#pragma unroll
        for (int k = 0; k < 64; k += 2) {
            acc0 = fmaf(rl(xv1, k),     wreg[64 + k],     acc0);
            acc1 = fmaf(rl(xv1, k + 1), wreg[64 + k + 1], acc1);
        }
        float xs = (lane == 0) ? 0.f : (acc0 + acc1 + bcol);

        float ss  = wsum64(xs * xs);
        float t   = sqrtf(ss + 1.0f);             // C = 1
        float nrm = sqrtf(ss + 1e-15f);
        float d0  = acoshf(fmaxf(t, 1.0f + 1e-6f));
        float scl = d0 / nrm;

        ox[(size_t)n * DD + lane] = (lane == 0) ? t : xs;
        float lxv = (lane == 0) ? 0.f : scl * xs;

        float aiv = wsum64(lxv * atti);
        float ajv = wsum64(lxv * attj);
        if (lane == 0) { ai[n] = aiv; snd[n] = make_float2(ajv, scl); }
    }
}

// ---------- CSR scan + place ----------
__global__ __launch_bounds__(256) void k_scan1(
    const int* __restrict__ deg, int* __restrict__ rowptr, int* __restrict__ bsum)
{
    __shared__ int tmp[256];
    int tid = threadIdx.x;
    int gid = blockIdx.x * 256 + tid;
    int v = (gid < NN) ? deg[gid] : 0;
    tmp[tid] = v; __syncthreads();
    for (int off = 1; off < 256; off <<= 1) {
        int t = (tid >= off) ? tmp[tid - off] : 0;
        __syncthreads();
        tmp[tid] += t;
        __syncthreads();
    }
    if (gid < NN) rowptr[gid + 1] = tmp[tid];
    if (tid == 255) bsum[blockIdx.x] = tmp[255];
}

__global__ __launch_bounds__(256) void k_scan2(int* __restrict__ bsum, int nb)
{
    __shared__ int tmp[256];
    int tid = threadIdx.x;
    int v = (tid < nb) ? bsum[tid] : 0;
    tmp[tid] = v; __syncthreads();
    for (int off = 1; off < 256; off <<= 1) {
        int t = (tid >= off) ? tmp[tid - off] : 0;
        __syncthreads();
        tmp[tid] += t;
        __syncthreads();
    }
    if (tid < nb) bsum[tid] = tmp[tid];
}

__global__ __launch_bounds__(256) void k_scan3(
    int* __restrict__ rowptr, const int* __restrict__ bsum)
{
    int gid = blockIdx.x * 256 + threadIdx.x;
    if (gid < NN) {
        int add = (blockIdx.x > 0) ? bsum[blockIdx.x - 1] : 0;
        rowptr[gid + 1] += add;
    }
    if (gid == 0) rowptr[0] = 0;
}

__global__ __launch_bounds__(256) void k_place(
    const int* __restrict__ ei0, const int* __restrict__ ei1,
    const int* __restrict__ rowptr, const int* __restrict__ posbuf,
    int* __restrict__ colA)
{
    int e = blockIdx.x * blockDim.x + threadIdx.x;
    if (e >= ETOT) return;
    int i, j;
    if (e < EE) { i = ei0[e]; j = ei1[e]; }
    else        { i = e - EE; j = i; }
    colA[rowptr[i] + posbuf[e]] = j;
}

// ---------- fused edge phase + epilogue: one wave per node ----------
__global__ __launch_bounds__(256) void k_fused(
    const int* __restrict__ rowptr, const int* __restrict__ colA,
    const float* __restrict__ ox, const float* __restrict__ ai,
    const float2* __restrict__ snd,
    float* __restrict__ ebuf, float* __restrict__ y)
{
    const int lane = threadIdx.x & 63;
    const int wid  = threadIdx.x >> 6;
    const int n = blockIdx.x * 4 + wid;
    if (n >= NN) return;

    const int base = rowptr[n];
    const int deg  = rowptr[n + 1] - base;
    const float aii = ai[n];
    const float xnv = ox[(size_t)n * DD + lane];   // wave-uniform row, 1 dim/lane

    float acc = 0.f;

    if (deg <= 64) {
        // ---- lane-per-edge: one gather round trip for the whole node ----
        const bool act = lane < deg;
        const int  ecl = min(lane, deg - 1);
        const int  jreg = colA[base + ecl];
        const float2 sv = snd[jreg];               // (aj, scl) 8B gather

        float inner = mink_inner(ox, jreg, xnv);
        float arg = fmaxf(-inner, 1.0f + 1e-6f);
        float dd0 = acoshf(arg);
        float sq  = act ? dd0 * dd0 : -3e38f;

        // ---- dense register softmax chain (lane k owns edge k) ----
        float m1 = wmax64(sq);
        float e1 = act ? expf(sq - m1) : 0.f;
        float s1 = wsum64(e1) + 1e-16f;
        float al = (aii + sv.x) * e1 / s1;
        al = (al >= 0.f) ? al : 0.2f * al;
        float m2 = wmax64(act ? al : -3e38f);
        float p2 = act ? expf(al - m2) : 0.f;
        float s2 = wsum64(p2);
        float w2 = p2 / (s2 + 1e-16f) * sv.y;      // fold scl_j

        // ---- sweep C: lane-per-dim, 8 row-gathers in flight (L2-warm) ----
        int k = 0;
        for (; k + 8 <= deg; k += 8) {
            float w0 = __shfl(w2, k + 0, 64), w1 = __shfl(w2, k + 1, 64);
            float w2b = __shfl(w2, k + 2, 64), w3 = __shfl(w2, k + 3, 64);
            float w4 = __shfl(w2, k + 4, 64), w5 = __shfl(w2, k + 5, 64);
            float w6 = __shfl(w2, k + 6, 64), w7 = __shfl(w2, k + 7, 64);
            int j0 = __shfl(jreg, k + 0, 64), j1 = __shfl(jreg, k + 1, 64);
            int j2 = __shfl(jreg, k + 2, 64), j3 = __shfl(jreg, k + 3, 64);
            int j4 = __shfl(jreg, k + 4, 64), j5 = __shfl(jreg, k + 5, 64);
            int j6 = __shfl(jreg, k + 6, 64), j7 = __shfl(jreg, k + 7, 64);
            float v0 = ox[(size_t)j0 * DD + lane], v1 = ox[(size_t)j1 * DD + lane];
            float v2 = ox[(size_t)j2 * DD + lane], v3 = ox[(size_t)j3 * DD + lane];
            float v4 = ox[(size_t)j4 * DD + lane], v5 = ox[(size_t)j5 * DD + lane];
            float v6 = ox[(size_t)j6 * DD + lane], v7 = ox[(size_t)j7 * DD + lane];
            acc = fmaf(w0, v0, acc);  acc = fmaf(w1, v1, acc);
            acc = fmaf(w2b, v2, acc); acc = fmaf(w3, v3, acc);
            acc = fmaf(w4, v4, acc);  acc = fmaf(w5, v5, acc);
            acc = fmaf(w6, v6, acc);  acc = fmaf(w7, v7, acc);
        }
        for (; k < deg; ++k) {
            float w = __shfl(w2, k, 64);
            int   j = __shfl(jreg, k, 64);
            acc = fmaf(w, ox[(size_t)j * DD + lane], acc);
        }
    } else {
        // ---- generic slow path (deg > 64): ebuf-based, ~never taken ----
        float m1 = -3e38f;
        for (int k0 = 0; k0 < deg; k0 += 64) {
            int e = k0 + lane;
            bool act = e < deg;
            int ec = min(e, deg - 1);
            int j = colA[base + ec];
            float inner = mink_inner(ox, j, xnv);
            float arg = fmaxf(-inner, 1.0f + 1e-6f);
            float dd0 = acoshf(arg);
            float sq = dd0 * dd0;
            if (act) ebuf[base + e] = sq;
            m1 = fmaxf(m1, act ? sq : -3e38f);
        }
        m1 = wmax64(m1);

        float s1p = 0.f;
        for (int k0 = 0; k0 < deg; k0 += 64) {
            int e = k0 + lane;
            if (e < deg) s1p += expf(ebuf[base + e] - m1);
        }
        float s1 = wsum64(s1p) + 1e-16f;

        float m2l = -3e38f;
        for (int k0 = 0; k0 < deg; k0 += 64) {
            int e = k0 + lane;
            if (e < deg) {
                int j = colA[base + e];
                float2 sv = snd[j];
                float al = (aii + sv.x) * expf(ebuf[base + e] - m1) / s1;
                al = (al >= 0.f) ? al : 0.2f * al;
                ebuf[base + e] = al;
                m2l = fmaxf(m2l, al);
            }
        }
        float m2 = wmax64(m2l);

        float s2p = 0.f;
        for (int k0 = 0; k0 < deg; k0 += 64) {
            int e = k0 + lane;
            if (e < deg) s2p += expf(ebuf[base + e] - m2);
        }
        float s2 = wsum64(s2p) + 1e-16f;

        for (int k = 0; k < deg; ++k) {
            int j = colA[base + k];
            float2 sv = snd[j];
            float w = expf(ebuf[base + k] - m2) / s2 * sv.y;
            acc = fmaf(w, ox[(size_t)j * DD + lane], acc);
        }
    }

    // ---- fused epilogue: relu + exp map ----
    float usp = (lane == 0) ? 0.f : fmaxf(acc, 0.f);
    float ss = wsum64(usp * usp);
    float un = sqrtf(ss + 1e-15f);
    float sc = sinhf(un) / un;
    float sp = sc * usp;
    float time = sqrtf(sc * sc * ss + 1.0f);
    y[(size_t)n * DD + lane] = (lane == 0) ? time : sp;
}

extern "C" void kernel_launch(void* const* d_in, const int* in_sizes, int n_in,
                              void* d_out, int out_size, void* d_ws, size_t ws_size,
                              hipStream_t stream) {
    const float* x   = (const float*)d_in[0];
    const float* W   = (const float*)d_in[1];
    const float* b   = (const float*)d_in[2];
    const float* att = (const float*)d_in[3];
    const int*   ei  = (const int*)d_in[4];
    const int* ei0 = ei;
    const int* ei1 = ei + EE;
    float* out = (float*)d_out;

    // workspace layout
    float*  ws  = (float*)d_ws;
    float*  ox  = ws;                                 // N*64
    float*  ai  = ox + (size_t)NN * DD;               // N
    float2* snd = (float2*)(ai + NN);                 // N float2 (8B aligned)
    int*    deg    = (int*)(snd + NN);                // N
    int*    rowptr = deg + NN;                        // N+1
    int*    bsum   = rowptr + NN + 1;                 // 256
    int*    colA   = bsum + 256;                      // ETOT
    int*    posbuf = colA + ETOT;                     // ETOT
    float*  ebuf   = (float*)posbuf;                  // overlay (slow path only)

    const int nb1 = (NN + 255) / 256;

    hipMemsetAsync(deg, 0, sizeof(int) * NN, stream);

    // fused node transform + degree count
    k_node_deg<<<NB_NODE + NB_EDGE, 256, 0, stream>>>(
        x, W, b, att, ei0, ox, ai, snd, deg, posbuf);

    // CSR scan + place
    k_scan1<<<nb1, 256, 0, stream>>>(deg, rowptr, bsum);
    k_scan2<<<1, 256, 0, stream>>>(bsum, nb1);
    k_scan3<<<nb1, 256, 0, stream>>>(rowptr, bsum);
    k_place<<<(ETOT + 255) / 256, 256, 0, stream>>>(ei0, ei1, rowptr, posbuf, colA);

    // fused edge phase + epilogue
    k_fused<<<(NN + 3) / 4, 256, 0, stream>>>(rowptr, colA, ox, ai, snd, ebuf, out);
}